// Round 1
// baseline (4080.808 us; speedup 1.0000x reference)
//
#include <hip/hip_runtime.h>
#include <math.h>

#define N_NODES 100000
#define N_EDGES 800000
#define NODE_IN 32
#define EDGE_DIM 84
#define HIDDEN 24
#define HEAD_HIDDEN 20
#define CAT_DIM 132            // 2*HIDDEN + EDGE_DIM
#define LN_EPS 1e-5f
#define TILE_E 64

__device__ __forceinline__ float gelu_exact(float x) {
    return 0.5f * x * (1.0f + erff(x * 0.70710678118654752f));
}

// ---------------- node input projection + intrinsic head ----------------
__global__ void k_node_in(const float* __restrict__ x,
                          const float* __restrict__ node_w, const float* __restrict__ node_b,
                          const float* __restrict__ ih_w1, const float* __restrict__ ih_b1,
                          const float* __restrict__ ih_w2, const float* __restrict__ ih_b2,
                          float* __restrict__ h, float* __restrict__ intr) {
    int n = blockIdx.x * blockDim.x + threadIdx.x;
    if (n >= N_NODES) return;
    float xv[NODE_IN];
    const float4* xp = (const float4*)(x + (size_t)n * NODE_IN);
#pragma unroll
    for (int i = 0; i < NODE_IN / 4; i++) {
        float4 v = xp[i];
        xv[4*i+0] = v.x; xv[4*i+1] = v.y; xv[4*i+2] = v.z; xv[4*i+3] = v.w;
    }
    float hv[HIDDEN];
#pragma unroll
    for (int j = 0; j < HIDDEN; j++) hv[j] = node_b[j];
    for (int k = 0; k < NODE_IN; k++) {
        float xk = xv[k];
#pragma unroll
        for (int j = 0; j < HIDDEN; j++) hv[j] = fmaf(xk, node_w[k * HIDDEN + j], hv[j]);
    }
    float* hp = h + (size_t)n * HIDDEN;
#pragma unroll
    for (int j = 0; j < HIDDEN; j++) hp[j] = hv[j];
    // intrinsic head
    float acc = ih_b2[0];
    for (int j = 0; j < HEAD_HIDDEN; j++) {
        float t = ih_b1[j];
#pragma unroll
        for (int k = 0; k < HIDDEN; k++) t = fmaf(hv[k], ih_w1[k * HEAD_HIDDEN + j], t);
        acc = fmaf(gelu_exact(t), ih_w2[j], acc);
    }
    intr[n] = acc;
}

// ---------------- in-degree counts ----------------
__global__ void k_counts(const int* __restrict__ ei, int* __restrict__ cnt) {
    int e = blockIdx.x * blockDim.x + threadIdx.x;
    if (e >= N_EDGES) return;
    atomicAdd(&cnt[ei[N_EDGES + e]], 1);
}

// ---------------- per-layer edge kernel: phi_e + LayerNorm -> e_out ----------------
// block = 256 threads = (x:32, y:8); TILE_E=64 edges per block
__global__ __launch_bounds__(256, 2)
void k_edge_e(const float* __restrict__ h, const float* __restrict__ e_in,
              const int* __restrict__ ei,
              const float* __restrict__ w1, const float* __restrict__ b1,
              const float* __restrict__ w2, const float* __restrict__ b2,
              const float* __restrict__ g, const float* __restrict__ bb,
              float* __restrict__ e_out) {
    __shared__ float s_cat[TILE_E][CAT_DIM];
    __shared__ float s_t[TILE_E][EDGE_DIM];
    __shared__ int s_src[TILE_E], s_dst[TILE_E];
    __shared__ float s_b1[EDGE_DIM], s_b2[EDGE_DIM], s_g[EDGE_DIM], s_bb[EDGE_DIM];

    int tid = threadIdx.x;
    int e0 = blockIdx.x * TILE_E;
    if (tid < TILE_E) {
        s_src[tid] = ei[e0 + tid];
        s_dst[tid] = ei[N_EDGES + e0 + tid];
    }
    if (tid < EDGE_DIM) {
        s_b1[tid] = b1[tid]; s_b2[tid] = b2[tid];
        s_g[tid]  = g[tid];  s_bb[tid] = bb[tid];
    }
    __syncthreads();

    // assemble cat = [h[src], h[dst], e]
    for (int idx = tid; idx < TILE_E * CAT_DIM; idx += 256) {
        int e = idx / CAT_DIM;
        int k = idx - e * CAT_DIM;
        float v;
        if (k < HIDDEN)            v = h[(size_t)s_src[e] * HIDDEN + k];
        else if (k < 2 * HIDDEN)   v = h[(size_t)s_dst[e] * HIDDEN + (k - HIDDEN)];
        else                       v = e_in[(size_t)(e0 + e) * EDGE_DIM + (k - 2 * HIDDEN)];
        s_cat[e][k] = v;
    }
    __syncthreads();

    const int x = tid & 31;     // col group base
    const int y = tid >> 5;     // 0..7, edge group
    // ---- GEMM1: t1 = gelu(cat @ w1 + b1), K=132, N=84 (cols x, x+32, x+64[<84]) ----
    float acc[8][3];
#pragma unroll
    for (int r = 0; r < 8; r++) { acc[r][0] = 0.f; acc[r][1] = 0.f; acc[r][2] = 0.f; }
    const bool has3 = (x < EDGE_DIM - 64);
    for (int k = 0; k < CAT_DIM; k++) {
        float wv0 = w1[k * EDGE_DIM + x];
        float wv1 = w1[k * EDGE_DIM + x + 32];
        float wv2 = has3 ? w1[k * EDGE_DIM + x + 64] : 0.f;
#pragma unroll
        for (int r = 0; r < 8; r++) {
            float cv = s_cat[y + 8 * r][k];
            acc[r][0] = fmaf(cv, wv0, acc[r][0]);
            acc[r][1] = fmaf(cv, wv1, acc[r][1]);
            acc[r][2] = fmaf(cv, wv2, acc[r][2]);
        }
    }
#pragma unroll
    for (int r = 0; r < 8; r++) {
        int e = y + 8 * r;
        s_t[e][x]      = gelu_exact(acc[r][0] + s_b1[x]);
        s_t[e][x + 32] = gelu_exact(acc[r][1] + s_b1[x + 32]);
        if (has3) s_t[e][x + 64] = gelu_exact(acc[r][2] + s_b1[x + 64]);
    }
    __syncthreads();

    // ---- GEMM2: r = e_old + t1 @ w2 + b2 (K=84), write into s_cat[e][48+j] ----
    float acc2[8][3];
#pragma unroll
    for (int r = 0; r < 8; r++) { acc2[r][0] = 0.f; acc2[r][1] = 0.f; acc2[r][2] = 0.f; }
    for (int k = 0; k < EDGE_DIM; k++) {
        float wv0 = w2[k * EDGE_DIM + x];
        float wv1 = w2[k * EDGE_DIM + x + 32];
        float wv2 = has3 ? w2[k * EDGE_DIM + x + 64] : 0.f;
#pragma unroll
        for (int r = 0; r < 8; r++) {
            float cv = s_t[y + 8 * r][k];
            acc2[r][0] = fmaf(cv, wv0, acc2[r][0]);
            acc2[r][1] = fmaf(cv, wv1, acc2[r][1]);
            acc2[r][2] = fmaf(cv, wv2, acc2[r][2]);
        }
    }
#pragma unroll
    for (int r = 0; r < 8; r++) {
        int e = y + 8 * r;
        s_cat[e][48 + x]      += acc2[r][0] + s_b2[x];
        s_cat[e][48 + x + 32] += acc2[r][1] + s_b2[x + 32];
        if (has3) s_cat[e][48 + x + 64] += acc2[r][2] + s_b2[x + 64];
    }
    __syncthreads();

    // ---- LayerNorm over 84 per edge: 4 threads per edge ----
    {
        int e = tid >> 2, p = tid & 3;
        float s = 0.f, sq = 0.f;
        for (int j = p; j < EDGE_DIM; j += 4) {
            float v = s_cat[e][48 + j];
            s += v; sq += v * v;
        }
        s  += __shfl_xor(s, 1);  s  += __shfl_xor(s, 2);
        sq += __shfl_xor(sq, 1); sq += __shfl_xor(sq, 2);
        float mean = s * (1.f / EDGE_DIM);
        float var  = sq * (1.f / EDGE_DIM) - mean * mean;
        float rstd = rsqrtf(var + LN_EPS);
        for (int j = p; j < EDGE_DIM; j += 4) {
            float v = (s_cat[e][48 + j] - mean) * rstd * s_g[j] + s_bb[j];
            s_cat[e][48 + j] = v;
        }
    }
    __syncthreads();

    // coalesced store of e_new
    for (int idx = tid; idx < TILE_E * EDGE_DIM; idx += 256) {
        int e = idx / EDGE_DIM;
        int j = idx - e * EDGE_DIM;
        e_out[(size_t)(e0 + e) * EDGE_DIM + j] = s_cat[e][48 + j];
    }
}

// ---------------- per-layer edge kernel: phi_v + scatter-add ----------------
__global__ __launch_bounds__(256, 3)
void k_edge_v(const float* __restrict__ h, const float* __restrict__ e_in,
              const int* __restrict__ ei,
              const float* __restrict__ v1, const float* __restrict__ vb1,
              const float* __restrict__ v2, const float* __restrict__ vb2,
              float* __restrict__ agg) {
    __shared__ float s_cat[TILE_E][CAT_DIM];
    __shared__ float s_t[TILE_E][HIDDEN];
    __shared__ float s_v2[HIDDEN * HIDDEN];
    __shared__ int s_src[TILE_E], s_dst[TILE_E];
    __shared__ float s_vb1[HIDDEN], s_vb2[HIDDEN];

    int tid = threadIdx.x;
    int e0 = blockIdx.x * TILE_E;
    if (tid < TILE_E) {
        s_src[tid] = ei[e0 + tid];
        s_dst[tid] = ei[N_EDGES + e0 + tid];
    }
    if (tid < HIDDEN) { s_vb1[tid] = vb1[tid]; s_vb2[tid] = vb2[tid]; }
    for (int idx = tid; idx < HIDDEN * HIDDEN; idx += 256) s_v2[idx] = v2[idx];
    __syncthreads();

    for (int idx = tid; idx < TILE_E * CAT_DIM; idx += 256) {
        int e = idx / CAT_DIM;
        int k = idx - e * CAT_DIM;
        float v;
        if (k < HIDDEN)          v = h[(size_t)s_src[e] * HIDDEN + k];
        else if (k < 2 * HIDDEN) v = h[(size_t)s_dst[e] * HIDDEN + (k - HIDDEN)];
        else                     v = e_in[(size_t)(e0 + e) * EDGE_DIM + (k - 2 * HIDDEN)];
        s_cat[e][k] = v;
    }
    __syncthreads();

    // mapping: jg = tid&7 -> cols jg*3..+2 ; eg = tid>>3 -> edges eg, eg+32
    const int jg = tid & 7;
    const int eg = tid >> 3;
    const int j0 = jg * 3;
    // ---- GEMM V1: t = gelu(cat @ v1 + b1), K=132, N=24 ----
    float acc[2][3];
#pragma unroll
    for (int r = 0; r < 2; r++) { acc[r][0] = 0.f; acc[r][1] = 0.f; acc[r][2] = 0.f; }
    for (int k = 0; k < CAT_DIM; k++) {
        float w0 = v1[k * HIDDEN + j0];
        float w1v = v1[k * HIDDEN + j0 + 1];
        float w2v = v1[k * HIDDEN + j0 + 2];
        float c0 = s_cat[eg][k];
        float c1 = s_cat[eg + 32][k];
        acc[0][0] = fmaf(c0, w0, acc[0][0]);
        acc[0][1] = fmaf(c0, w1v, acc[0][1]);
        acc[0][2] = fmaf(c0, w2v, acc[0][2]);
        acc[1][0] = fmaf(c1, w0, acc[1][0]);
        acc[1][1] = fmaf(c1, w1v, acc[1][1]);
        acc[1][2] = fmaf(c1, w2v, acc[1][2]);
    }
#pragma unroll
    for (int r = 0; r < 2; r++) {
        int e = eg + 32 * r;
        s_t[e][j0]     = gelu_exact(acc[r][0] + s_vb1[j0]);
        s_t[e][j0 + 1] = gelu_exact(acc[r][1] + s_vb1[j0 + 1]);
        s_t[e][j0 + 2] = gelu_exact(acc[r][2] + s_vb1[j0 + 2]);
    }
    __syncthreads();

    // ---- GEMM V2: m = t @ v2 + b2, K=24, N=24 ----
    float acc2[2][3];
#pragma unroll
    for (int r = 0; r < 2; r++) { acc2[r][0] = 0.f; acc2[r][1] = 0.f; acc2[r][2] = 0.f; }
    for (int k = 0; k < HIDDEN; k++) {
        float w0 = s_v2[k * HIDDEN + j0];
        float w1v = s_v2[k * HIDDEN + j0 + 1];
        float w2v = s_v2[k * HIDDEN + j0 + 2];
        float c0 = s_t[eg][k];
        float c1 = s_t[eg + 32][k];
        acc2[0][0] = fmaf(c0, w0, acc2[0][0]);
        acc2[0][1] = fmaf(c0, w1v, acc2[0][1]);
        acc2[0][2] = fmaf(c0, w2v, acc2[0][2]);
        acc2[1][0] = fmaf(c1, w0, acc2[1][0]);
        acc2[1][1] = fmaf(c1, w1v, acc2[1][1]);
        acc2[1][2] = fmaf(c1, w2v, acc2[1][2]);
    }
#pragma unroll
    for (int r = 0; r < 2; r++) {
        int e = eg + 32 * r;
        int d = s_dst[e];
        atomicAdd(&agg[(size_t)d * HIDDEN + j0],     acc2[r][0] + s_vb2[j0]);
        atomicAdd(&agg[(size_t)d * HIDDEN + j0 + 1], acc2[r][1] + s_vb2[j0 + 1]);
        atomicAdd(&agg[(size_t)d * HIDDEN + j0 + 2], acc2[r][2] + s_vb2[j0 + 2]);
    }
}

// ---------------- node update: h = LN(h + agg/counts) ----------------
__global__ void k_node_up(float* __restrict__ h, const float* __restrict__ agg,
                          const int* __restrict__ cnt,
                          const float* __restrict__ g, const float* __restrict__ b) {
    int n = blockIdx.x * blockDim.x + threadIdx.x;
    if (n >= N_NODES) return;
    int c = cnt[n]; if (c < 1) c = 1;
    float inv = 1.0f / (float)c;
    float v[HIDDEN];
    float s = 0.f;
#pragma unroll
    for (int j = 0; j < HIDDEN; j++) {
        v[j] = h[(size_t)n * HIDDEN + j] + agg[(size_t)n * HIDDEN + j] * inv;
        s += v[j];
    }
    float mean = s * (1.f / HIDDEN);
    float sq = 0.f;
#pragma unroll
    for (int j = 0; j < HIDDEN; j++) { float d = v[j] - mean; sq = fmaf(d, d, sq); }
    float rstd = rsqrtf(sq * (1.f / HIDDEN) + LN_EPS);
#pragma unroll
    for (int j = 0; j < HIDDEN; j++)
        h[(size_t)n * HIDDEN + j] = (v[j] - mean) * rstd * g[j] + b[j];
}

// ---------------- final: out = mu + intrinsic + context(h) ----------------
__global__ void k_final(const float* __restrict__ h, const float* __restrict__ intr,
                        const float* __restrict__ ch_w1, const float* __restrict__ ch_b1,
                        const float* __restrict__ ch_w2, const float* __restrict__ ch_b2,
                        const float* __restrict__ mu, float* __restrict__ out) {
    int n = blockIdx.x * blockDim.x + threadIdx.x;
    if (n >= N_NODES) return;
    float hv[HIDDEN];
#pragma unroll
    for (int j = 0; j < HIDDEN; j++) hv[j] = h[(size_t)n * HIDDEN + j];
    float acc = ch_b2[0];
    for (int j = 0; j < HEAD_HIDDEN; j++) {
        float t = ch_b1[j];
#pragma unroll
        for (int k = 0; k < HIDDEN; k++) t = fmaf(hv[k], ch_w1[k * HEAD_HIDDEN + j], t);
        acc = fmaf(gelu_exact(t), ch_w2[j], acc);
    }
    out[n] = mu[0] + intr[n] + acc;
}

extern "C" void kernel_launch(void* const* d_in, const int* in_sizes, int n_in,
                              void* d_out, int out_size, void* d_ws, size_t ws_size,
                              hipStream_t stream) {
    const float* x        = (const float*)d_in[0];
    const float* edge_attr= (const float*)d_in[1];
    const float* node_w   = (const float*)d_in[2];
    const float* node_b   = (const float*)d_in[3];
    const float* ih_w1    = (const float*)d_in[4];
    const float* ih_b1    = (const float*)d_in[5];
    const float* ih_w2    = (const float*)d_in[6];
    const float* ih_b2    = (const float*)d_in[7];
    const float* pe_w1    = (const float*)d_in[8];
    const float* pe_b1    = (const float*)d_in[9];
    const float* pe_w2    = (const float*)d_in[10];
    const float* pe_b2    = (const float*)d_in[11];
    const float* pv_w1    = (const float*)d_in[12];
    const float* pv_b1    = (const float*)d_in[13];
    const float* pv_w2    = (const float*)d_in[14];
    const float* pv_b2    = (const float*)d_in[15];
    const float* ne_g     = (const float*)d_in[16];
    const float* ne_b     = (const float*)d_in[17];
    const float* nv_g     = (const float*)d_in[18];
    const float* nv_b     = (const float*)d_in[19];
    const float* ch_w1    = (const float*)d_in[20];
    const float* ch_b1    = (const float*)d_in[21];
    const float* ch_w2    = (const float*)d_in[22];
    const float* ch_b2    = (const float*)d_in[23];
    const float* mu       = (const float*)d_in[24];
    const int*   ei       = (const int*)d_in[25];

    char* ws = (char*)d_ws;
    float* h    = (float*)ws; ws += (size_t)N_NODES * HIDDEN * 4;
    float* agg  = (float*)ws; ws += (size_t)N_NODES * HIDDEN * 4;
    float* intr = (float*)ws; ws += (size_t)N_NODES * 4;
    int*   cnt  = (int*)ws;   ws += (size_t)N_NODES * 4;
    float* e_ws = (float*)ws; ws += (size_t)N_EDGES * EDGE_DIM * 4;

    hipMemsetAsync(cnt, 0, (size_t)N_NODES * 4, stream);
    k_counts<<<(N_EDGES + 255) / 256, 256, 0, stream>>>(ei, cnt);
    k_node_in<<<(N_NODES + 255) / 256, 256, 0, stream>>>(
        x, node_w, node_b, ih_w1, ih_b1, ih_w2, ih_b2, h, intr);

    const int eb = N_EDGES / TILE_E;  // 12500, exact
    for (int L = 0; L < 2; L++) {
        const float* ein = (L == 0) ? edge_attr : e_ws;
        k_edge_e<<<eb, 256, 0, stream>>>(
            h, ein, ei,
            pe_w1 + (size_t)L * CAT_DIM * EDGE_DIM, pe_b1 + (size_t)L * EDGE_DIM,
            pe_w2 + (size_t)L * EDGE_DIM * EDGE_DIM, pe_b2 + (size_t)L * EDGE_DIM,
            ne_g + (size_t)L * EDGE_DIM, ne_b + (size_t)L * EDGE_DIM, e_ws);
        hipMemsetAsync(agg, 0, (size_t)N_NODES * HIDDEN * 4, stream);
        k_edge_v<<<eb, 256, 0, stream>>>(
            h, e_ws, ei,
            pv_w1 + (size_t)L * CAT_DIM * HIDDEN, pv_b1 + (size_t)L * HIDDEN,
            pv_w2 + (size_t)L * HIDDEN * HIDDEN, pv_b2 + (size_t)L * HIDDEN, agg);
        k_node_up<<<(N_NODES + 255) / 256, 256, 0, stream>>>(
            h, agg, cnt, nv_g + (size_t)L * HIDDEN, nv_b + (size_t)L * HIDDEN);
    }
    k_final<<<(N_NODES + 255) / 256, 256, 0, stream>>>(
        h, intr, ch_w1, ch_b1, ch_w2, ch_b2, mu, (float*)d_out);
}